// Round 3
// baseline (951.875 us; speedup 1.0000x reference)
//
#include <hip/hip_runtime.h>

#define DEPTH   4
#define BSZ     2
#define LSEQ    1024
#define DMODEL  1024
#define NHEAD   16
#define HDIM    64
#define MROWS   (BSZ*LSEQ)    // 2048
#define INNER   2730
#define INNERP  2752
#define N1      (2*INNER)     // 5460
#define N1P     (2*INNERP)    // 5504
#define LOG2E   1.4426950408889634f

typedef __bf16 bf16;
typedef bf16  bf16x8 __attribute__((ext_vector_type(8)));
typedef float f32x4  __attribute__((ext_vector_type(4)));
typedef uint32_t u32x4 __attribute__((ext_vector_type(4)));

__device__ inline f32x4 mfma16(bf16x8 a, bf16x8 b, f32x4 c) {
  return __builtin_amdgcn_mfma_f32_16x16x32_bf16(a, b, c, 0, 0, 0);
}

__device__ inline void gload_lds16(const void* g, void* l) {
  __builtin_amdgcn_global_load_lds(
      (const __attribute__((address_space(1))) void*)g,
      (__attribute__((address_space(3))) void*)l, 16, 0, 0);
}

// ---------------- weight conversion ----------------
__global__ void conv_bf16_kernel(const float* __restrict__ src, bf16* __restrict__ dst, size_t n) {
  size_t i = ((size_t)blockIdx.x * 256 + threadIdx.x) * 4;
  if (i >= n) return;
  float4 v = *(const float4*)(src + i);
  dst[i+0] = (bf16)v.x; dst[i+1] = (bf16)v.y; dst[i+2] = (bf16)v.z; dst[i+3] = (bf16)v.w;
}

// ff_w1 (DEPTH,5460,1024) -> padded interleaved (DEPTH,5504,1024):
// padded row rp: p=rp>>4, w=rp&15, col=(p>>1)*16+w; even p -> a-row col,
// odd p -> gate-row INNER+col; col>=INNER -> zero.
__global__ void conv_w1_kernel(const float* __restrict__ src, bf16* __restrict__ dst) {
  size_t i = ((size_t)blockIdx.x * 256 + threadIdx.x) * 4;
  const size_t tot = (size_t)DEPTH * N1P * DMODEL;
  if (i >= tot) return;
  int d  = (int)(i / ((size_t)N1P * DMODEL));
  int rem = (int)(i % ((size_t)N1P * DMODEL));
  int rp = rem / DMODEL, k = rem % DMODEL;
  int p2 = rp >> 4, w = rp & 15;
  int col = ((p2 >> 1) << 4) + w;
  if (col >= INNER) {
    dst[i+0] = (bf16)0.f; dst[i+1] = (bf16)0.f; dst[i+2] = (bf16)0.f; dst[i+3] = (bf16)0.f;
    return;
  }
  int rs = (p2 & 1) ? (INNER + col) : col;
  const float* s = src + ((size_t)d * N1 + rs) * DMODEL + k;
  float4 v = *(const float4*)s;
  dst[i+0] = (bf16)v.x; dst[i+1] = (bf16)v.y; dst[i+2] = (bf16)v.z; dst[i+3] = (bf16)v.w;
}

__global__ void conv_b1_kernel(const float* __restrict__ src, float* __restrict__ dst) {
  int i = blockIdx.x * 256 + threadIdx.x;
  if (i >= DEPTH * N1P) return;
  int d = i / N1P, rp = i % N1P;
  int p2 = rp >> 4, w = rp & 15;
  int col = ((p2 >> 1) << 4) + w;
  float v = 0.f;
  if (col < INNER) v = src[d * N1 + ((p2 & 1) ? (INNER + col) : col)];
  dst[i] = v;
}

__global__ void conv_w2_kernel(const float* __restrict__ src, bf16* __restrict__ dst) {
  size_t i = ((size_t)blockIdx.x * 256 + threadIdx.x) * 4;
  const size_t tot = (size_t)DEPTH * DMODEL * INNERP;
  if (i >= tot) return;
  size_t dn = i / INNERP;
  int kp = (int)(i % INNERP);
  const float* s = src + dn * INNER;
  for (int j = 0; j < 4; ++j) {
    int k = kp + j;
    dst[i+j] = (k < INNER) ? (bf16)s[k] : (bf16)0.f;
  }
}

// ---------------- RMSNorm ----------------
template<bool OUT_BF16>
__global__ __launch_bounds__(256) void rmsnorm_kernel(const float* __restrict__ x,
    const float* __restrict__ gamma, void* __restrict__ out) {
  const int row = blockIdx.x;
  const int tid = threadIdx.x;
  const float4 v = *(const float4*)(x + (size_t)row * DMODEL + tid * 4);
  float ss = v.x*v.x + v.y*v.y + v.z*v.z + v.w*v.w;
  for (int m = 1; m < 64; m <<= 1) ss += __shfl_xor(ss, m);
  __shared__ float ws4[4];
  if ((tid & 63) == 0) ws4[tid >> 6] = ss;
  __syncthreads();
  float tot = ws4[0] + ws4[1] + ws4[2] + ws4[3];
  float scale = 32.0f / fmaxf(sqrtf(tot), 1e-12f);
  const float4 g = *(const float4*)(gamma + tid * 4);
  float o0 = v.x*scale*g.x, o1 = v.y*scale*g.y, o2 = v.z*scale*g.z, o3 = v.w*scale*g.w;
  size_t p = (size_t)row * DMODEL + tid * 4;
  if (OUT_BF16) {
    bf16* ob = (bf16*)out;
    ob[p+0] = (bf16)o0; ob[p+1] = (bf16)o1; ob[p+2] = (bf16)o2; ob[p+3] = (bf16)o3;
  } else {
    *(float4*)((float*)out + p) = make_float4(o0, o1, o2, o3);
  }
}

// ---------------- GEMM: C(MxN) = A(MxK) @ W(NxK)^T + bias [+ res] ----------------
// EPI: 0 = bf16 out, 1 = f32 out + residual add, 2 = fused GEGLU (interleaved
// a/gate column pairs at 16-granularity; output N_/2 wide bf16).
template<int TN, int EPI>
__global__ __launch_bounds__(256) void gemm_bt(const bf16* __restrict__ A,
    const bf16* __restrict__ Bw, const float* __restrict__ bias,
    const float* __restrict__ res, void* __restrict__ Cout,
    int M_, int N_, int K_) {
  constexpr int NFR = TN / 32;
  constexpr int BCH = TN / 32;
  __shared__ __attribute__((aligned(16))) bf16 As[128 * 64];
  __shared__ __attribute__((aligned(16))) bf16 Bs[TN * 64];
  const int tid  = threadIdx.x;
  const int lane = tid & 63;
  const int wid  = tid >> 6;
  const int wr = wid >> 1, wc = wid & 1;
  const int m0 = blockIdx.y * 128;
  const int n0 = blockIdx.x * TN;

  f32x4 acc[4][NFR] = {};
  const int nk = K_ >> 6;
  for (int kt = 0; kt < nk; ++kt) {
    const int k0 = kt << 6;
    #pragma unroll
    for (int j = 0; j < 4; ++j) {
      int c = j * 256 + tid;
      int row = c >> 3;
      int col = (c & 7) << 3;
      int ldsbase = (j * 256 + wid * 64) << 3;
      gload_lds16(A + (size_t)(m0 + row) * K_ + k0 + col, As + ldsbase);
    }
    #pragma unroll
    for (int j = 0; j < BCH; ++j) {
      int c = j * 256 + tid;
      int row = c >> 3;
      int col = (c & 7) << 3;
      int ldsbase = (j * 256 + wid * 64) << 3;
      gload_lds16(Bw + (size_t)(n0 + row) * K_ + k0 + col, Bs + ldsbase);
    }
    asm volatile("s_waitcnt vmcnt(0)" ::: "memory");
    __syncthreads();

    #pragma unroll
    for (int kk = 0; kk < 2; ++kk) {
      const int krow = kk * 32 + ((lane >> 4) << 3);
      bf16x8 af[4], bfr[NFR];
      #pragma unroll
      for (int m = 0; m < 4; ++m)
        af[m] = *(const bf16x8*)(As + (wr*64 + m*16 + (lane & 15)) * 64 + krow);
      #pragma unroll
      for (int n = 0; n < NFR; ++n)
        bfr[n] = *(const bf16x8*)(Bs + (wc*(TN/2) + n*16 + (lane & 15)) * 64 + krow);
      #pragma unroll
      for (int m = 0; m < 4; ++m)
        #pragma unroll
        for (int n = 0; n < NFR; ++n)
          acc[m][n] = mfma16(af[m], bfr[n], acc[m][n]);
    }
    __syncthreads();
  }

  const int rb = (lane >> 4) << 2;
  const int cl = lane & 15;
  if (EPI == 2) {
    #pragma unroll
    for (int m = 0; m < 4; ++m) {
      #pragma unroll
      for (int np = 0; np < NFR/2; ++np) {
        int ca = n0 + wc*(TN/2) + (2*np)*16 + cl;   // padded a-col
        int cg = ca + 16;                            // padded gate-col
        float ba = bias[ca], bg = bias[cg];
        int colo = ((ca >> 5) << 4) + cl;            // output col in [0, N_/2)
        #pragma unroll
        for (int r = 0; r < 4; ++r) {
          int row = m0 + wr*64 + m*16 + rb + r;
          float av = acc[m][2*np][r] + ba;
          float gv = acc[m][2*np+1][r] + bg;
          float gl = 0.5f * gv * (1.f + erff(gv * 0.70710678118654752f));
          ((bf16*)Cout)[(size_t)row * (N_ >> 1) + colo] = (bf16)(av * gl);
        }
      }
    }
  } else {
    #pragma unroll
    for (int m = 0; m < 4; ++m) {
      #pragma unroll
      for (int n = 0; n < NFR; ++n) {
        int col = n0 + wc*(TN/2) + n*16 + cl;
        float bv = bias[col];
        #pragma unroll
        for (int r = 0; r < 4; ++r) {
          int row = m0 + wr*64 + m*16 + rb + r;
          float v = acc[m][n][r] + bv;
          size_t p = (size_t)row * N_ + col;
          if (EPI == 1) ((float*)Cout)[p] = v + res[p];
          else          ((bf16*)Cout)[p] = (bf16)v;
        }
      }
    }
  }
}

// ---------------- Flash attention, split-KV=2, ALiBi, KVBLK=64 ----------------
__global__ __launch_bounds__(256) void attn_kernel(const bf16* __restrict__ qkv,
    const float* __restrict__ slopes, float* __restrict__ Opart, float* __restrict__ ml) {
  const int tid = threadIdx.x, lane = tid & 63, wid = tid >> 6;
  const int bh = blockIdx.y;
  const int b = bh >> 4, h = bh & 15;
  const int kvz = blockIdx.z;
  const int kv0 = kvz * (LSEQ/2);
  const float slope2 = slopes[h] * LOG2E;
  const float SC = 0.125f * LOG2E;
  const int qw = blockIdx.x * 64 + wid * 16;

  __shared__ __attribute__((aligned(16))) bf16     Kt[64 * 72];
  __shared__ __attribute__((aligned(16))) uint32_t V32[64 * 36];
  __shared__ __attribute__((aligned(16))) uint32_t Pl32[4][16 * 36];

  const size_t rs = 3 * DMODEL;
  const size_t base = (size_t)b * LSEQ * rs;

  bf16x8 qf[2];
  {
    const bf16* p = qkv + base + (size_t)(qw + (lane & 15)) * rs + h * HDIM + ((lane >> 4) << 3);
    qf[0] = *(const bf16x8*)p;
    qf[1] = *(const bf16x8*)(p + 32);
  }

  f32x4 accO[4] = {};
  float mrow[4], lrow[4];
  #pragma unroll
  for (int r = 0; r < 4; ++r) { mrow[r] = -1e30f; lrow[r] = 0.f; }

  const int trow = tid >> 2;
  const int tcol = (tid & 3) << 4;

  bf16x8 kreg0, kreg1, vreg0, vreg1;
  {
    const bf16* kp = qkv + base + (size_t)(kv0 + trow) * rs + DMODEL + h * HDIM + tcol;
    kreg0 = *(const bf16x8*)kp; kreg1 = *(const bf16x8*)(kp + 8);
    const bf16* vp = qkv + base + (size_t)(kv0 + trow) * rs + 2 * DMODEL + h * HDIM + tcol;
    vreg0 = *(const bf16x8*)vp; vreg1 = *(const bf16x8*)(vp + 8);
  }

  uint32_t* P32w = &Pl32[wid][0];
  const int q = lane & 15, G = lane >> 4;

  for (int kv = kv0; kv < kv0 + LSEQ/2; kv += 64) {
    __syncthreads();
    *(bf16x8*)(Kt + trow * 72 + tcol)     = kreg0;
    *(bf16x8*)(Kt + trow * 72 + tcol + 8) = kreg1;
    {
      u32x4 va = __builtin_bit_cast(u32x4, vreg0);
      u32x4 vb = __builtin_bit_cast(u32x4, vreg1);
      u32x4 pa, pb;
      #pragma unroll
      for (int i = 0; i < 4; ++i) {
        pa[i] = (uint32_t)__shfl_xor((int)va[i], 4);
        pb[i] = (uint32_t)__shfl_xor((int)vb[i], 4);
      }
      const bool oddk = (trow & 1);
      const int d0 = tcol + (oddk ? 8 : 0);
      u32x4 m = oddk ? vb : va;
      u32x4 oo = oddk ? pb : pa;
      const int kpair = trow >> 1;
      const int swz = kpair ^ ((d0 >> 3) << 1);
      #pragma unroll
      for (int i = 0; i < 4; ++i) {
        uint32_t lo = oddk ? oo[i] : m[i];
        uint32_t hi = oddk ? m[i] : oo[i];
        uint32_t w0 = (lo & 0xffffu) | (hi << 16);
        uint32_t w1 = (lo >> 16) | (hi & 0xffff0000u);
        V32[(d0 + 2*i)     * 36 + swz] = w0;
        V32[(d0 + 2*i + 1) * 36 + swz] = w1;
      }
    }
    __syncthreads();

    if (kv + 64 < kv0 + LSEQ/2) {
      const bf16* kp = qkv + base + (size_t)(kv + 64 + trow) * rs + DMODEL + h * HDIM + tcol;
      kreg0 = *(const bf16x8*)kp; kreg1 = *(const bf16x8*)(kp + 8);
      const bf16* vp = qkv + base + (size_t)(kv + 64 + trow) * rs + 2 * DMODEL + h * HDIM + tcol;
      vreg0 = *(const bf16x8*)vp; vreg1 = *(const bf16x8*)(vp + 8);
    }

    f32x4 sacc[4] = {};
    __builtin_amdgcn_s_setprio(1);
    #pragma unroll
    for (int nt = 0; nt < 4; ++nt) {
      const bf16* kb = Kt + (nt * 16 + q) * 72 + (G << 3);
      sacc[nt] = mfma16(qf[0], *(const bf16x8*)kb, sacc[nt]);
      sacc[nt] = mfma16(qf[1], *(const bf16x8*)(kb + 32), sacc[nt]);
    }
    __builtin_amdgcn_s_setprio(0);

    float pv[4][4];
    #pragma unroll
    for (int r = 0; r < 4; ++r) {
      int qi = qw + (G << 2) + r;
      float vmax = -1e30f;
      #pragma unroll
      for (int nt = 0; nt < 4; ++nt) {
        int kj = kv + nt * 16 + q;
        float s = sacc[nt][r] * SC - slope2 * fabsf((float)(qi - kj));
        pv[nt][r] = s;
        vmax = fmaxf(vmax, s);
      }
      for (int m = 1; m < 16; m <<= 1) vmax = fmaxf(vmax, __shfl_xor(vmax, m));
      float newmax = fmaxf(mrow[r], vmax);
      float ef = exp2f(mrow[r] - newmax);
      float rsum = 0.f;
      #pragma unroll
      for (int nt = 0; nt < 4; ++nt) {
        float p = exp2f(pv[nt][r] - newmax);
        pv[nt][r] = p;
        rsum += p;
      }
      for (int m = 1; m < 16; m <<= 1) rsum += __shfl_xor(rsum, m);
      lrow[r] = lrow[r] * ef + rsum;
      mrow[r] = newmax;
      #pragma unroll
      for (int dn = 0; dn < 4; ++dn) accO[dn][r] *= ef;
    }

    #pragma unroll
    for (int nt = 0; nt < 4; ++nt) {
      #pragma unroll
      for (int r = 0; r < 4; ++r) {
        float other = __shfl_xor(pv[nt][r], 1);
        if (!(lane & 1)) {
          uint32_t w;
          asm("v_cvt_pk_bf16_f32 %0, %1, %2" : "=v"(w) : "v"(pv[nt][r]), "v"(other));
          int prow = (G << 2) + r;
          int col2 = nt * 8 + (q >> 1);
          P32w[prow * 36 + (col2 ^ ((prow & 7) << 1))] = w;
        }
      }
    }
    asm volatile("s_waitcnt lgkmcnt(0)" ::: "memory");

    __builtin_amdgcn_s_setprio(1);
    #pragma unroll
    for (int chunk = 0; chunk < 2; ++chunk) {
      u32x4 praw = *(const u32x4*)(P32w + q * 36 + chunk * 16 + 4 * (G ^ ((q >> 1) & 3)));
      if (q & 1) praw = __builtin_shufflevector(praw, praw, 2, 3, 0, 1);
      bf16x8 pf = __builtin_bit_cast(bf16x8, praw);
      #pragma unroll
      for (int dn = 0; dn < 4; ++dn) {
        const int d = dn * 16 + q;
        u32x4 raw = *(const u32x4*)(V32 + d * 36 + chunk * 16 + 4 * (G ^ dn));
        if ((lane >> 3) & 1) raw = __builtin_shufflevector(raw, raw, 2, 3, 0, 1);
        bf16x8 vf = __builtin_bit_cast(bf16x8, raw);
        accO[dn] = mfma16(pf, vf, accO[dn]);
      }
    }
    __builtin_amdgcn_s_setprio(0);
  }

  #pragma unroll
  for (int r = 0; r < 4; ++r) {
    int qr = qw + (G << 2) + r;
    size_t obase = ((size_t)(kvz * 32 + bh) * LSEQ + qr) * HDIM;
    #pragma unroll
    for (int dn = 0; dn < 4; ++dn)
      Opart[obase + dn * 16 + q] = accO[dn][r];
    if (q == 0) {
      size_t mb = ((size_t)(kvz * 32 + bh) * LSEQ + qr) * 2;
      ml[mb]     = mrow[r];
      ml[mb + 1] = lrow[r];
    }
  }
}

// combine two kv-halves: O = (O0*e^{m0-m} + O1*e^{m1-m}) / (l0*e^{m0-m} + l1*e^{m1-m})
__global__ __launch_bounds__(256) void attn_combine(const float* __restrict__ Opart,
    const float* __restrict__ ml, bf16* __restrict__ o) {
  int idx = blockIdx.x * 256 + threadIdx.x;   // 524288 total
  int bh = idx >> 14;
  int rem = idx & 16383;
  int qr = rem >> 4;
  int d4 = (rem & 15) << 2;
  size_t r0 = (size_t)bh * LSEQ + qr;
  size_t r1 = (size_t)(32 + bh) * LSEQ + qr;
  float m0 = ml[r0*2], l0 = ml[r0*2+1];
  float m1 = ml[r1*2], l1 = ml[r1*2+1];
  float m = fmaxf(m0, m1);
  float w0 = exp2f(m0 - m), w1 = exp2f(m1 - m);
  float inv = 1.f / (l0 * w0 + l1 * w1);
  float4 o0 = *(const float4*)(Opart + r0 * HDIM + d4);
  float4 o1 = *(const float4*)(Opart + r1 * HDIM + d4);
  int b = bh >> 4, h = bh & 15;
  bf16* op = o + ((size_t)(b * LSEQ + qr) * DMODEL + h * HDIM + d4);
  op[0] = (bf16)((o0.x*w0 + o1.x*w1) * inv);
  op[1] = (bf16)((o0.y*w0 + o1.y*w1) * inv);
  op[2] = (bf16)((o0.z*w0 + o1.z*w1) * inv);
  op[3] = (bf16)((o0.w*w0 + o1.w*w1) * inv);
}

// ---------------- host ----------------
extern "C" void kernel_launch(void* const* d_in, const int* in_sizes, int n_in,
                              void* d_out, int out_size, void* d_ws, size_t ws_size,
                              hipStream_t stream) {
  const float* x_in      = (const float*)d_in[0];
  const float* slopes    = (const float*)d_in[1];
  const float* g_attn    = (const float*)d_in[2];
  const float* w_in      = (const float*)d_in[3];
  const float* b_in      = (const float*)d_in[4];
  const float* w_out     = (const float*)d_in[5];
  const float* b_out     = (const float*)d_in[6];
  const float* g_ff      = (const float*)d_in[7];
  const float* w1        = (const float*)d_in[8];
  const float* b1        = (const float*)d_in[9];
  const float* w2        = (const float*)d_in[10];
  const float* b2        = (const float*)d_in[11];
  const float* g_final   = (const float*)d_in[12];

  char* p = (char*)d_ws;
  float* xw   = (float*)p;              p += (size_t)MROWS * DMODEL * 4;
  bf16* abuf  = (bf16*)p;               p += (size_t)MROWS * DMODEL * 2;
  bf16* qkvb  = (bf16*)p;               p += (size_t)MROWS * 3 * DMODEL * 2;
  bf16* obuf  = (bf16*)p;               p += (size_t)MROWS * DMODEL * 2;
  bf16* gbuf  = (bf16*)p;               p += (size_t)MROWS * INNERP * 2;
  float* Opart = (float*)p;             p += (size_t)2 * 32 * LSEQ * HDIM * 4;
  float* mlb   = (float*)p;             p += (size_t)2 * 32 * LSEQ * 2 * 4;
  bf16* w_in_b  = (bf16*)p;             p += (size_t)DEPTH * 3 * DMODEL * DMODEL * 2;
  bf16* w_out_b = (bf16*)p;             p += (size_t)DEPTH * DMODEL * DMODEL * 2;
  bf16* w1p     = (bf16*)p;             p += (size_t)DEPTH * N1P * DMODEL * 2;
  bf16* w2p     = (bf16*)p;             p += (size_t)DEPTH * DMODEL * INNERP * 2;
  float* b1p    = (float*)p;            p += (size_t)DEPTH * N1P * 4;

  hipMemcpyAsync(xw, x_in, (size_t)MROWS * DMODEL * 4, hipMemcpyDeviceToDevice, stream);

  conv_bf16_kernel<<<12288, 256, 0, stream>>>(w_in, w_in_b, (size_t)DEPTH * 3 * DMODEL * DMODEL);
  conv_bf16_kernel<<<4096, 256, 0, stream>>>(w_out, w_out_b, (size_t)DEPTH * DMODEL * DMODEL);
  conv_w1_kernel<<<22016, 256, 0, stream>>>(w1, w1p);
  conv_b1_kernel<<<86, 256, 0, stream>>>(b1, b1p);
  conv_w2_kernel<<<11008, 256, 0, stream>>>(w2, w2p);

  for (int i = 0; i < DEPTH; ++i) {
    rmsnorm_kernel<true><<<MROWS, 256, 0, stream>>>(xw, g_attn + i * DMODEL, abuf);
    gemm_bt<64, 0><<<dim3(48, 16), 256, 0, stream>>>(
        abuf, w_in_b + (size_t)i * 3 * DMODEL * DMODEL, b_in + i * 3 * DMODEL,
        nullptr, qkvb, MROWS, 3 * DMODEL, DMODEL);
    attn_kernel<<<dim3(16, 32, 2), 256, 0, stream>>>(qkvb, slopes, Opart, mlb);
    attn_combine<<<2048, 256, 0, stream>>>(Opart, mlb, obuf);
    gemm_bt<64, 1><<<dim3(16, 16), 256, 0, stream>>>(
        obuf, w_out_b + (size_t)i * DMODEL * DMODEL, b_out + i * DMODEL,
        xw, xw, MROWS, DMODEL, DMODEL);
    rmsnorm_kernel<true><<<MROWS, 256, 0, stream>>>(xw, g_ff + i * DMODEL, abuf);
    gemm_bt<128, 2><<<dim3(43, 16), 256, 0, stream>>>(
        abuf, w1p + (size_t)i * N1P * DMODEL, b1p + i * N1P,
        nullptr, gbuf, MROWS, N1P, DMODEL);
    gemm_bt<64, 1><<<dim3(16, 16), 256, 0, stream>>>(
        gbuf, w2p + (size_t)i * DMODEL * INNERP, b2 + i * DMODEL,
        xw, xw, MROWS, DMODEL, INNERP);
  }
  rmsnorm_kernel<false><<<MROWS, 256, 0, stream>>>(xw, g_final, d_out);
}

// Round 4
// 842.189 us; speedup vs baseline: 1.1302x; 1.1302x over previous
//
#include <hip/hip_runtime.h>

#define DEPTH   4
#define BSZ     2
#define LSEQ    1024
#define DMODEL  1024
#define NHEAD   16
#define HDIM    64
#define MROWS   (BSZ*LSEQ)    // 2048
#define INNER   2730
#define INNERP  2752
#define N1      (2*INNER)     // 5460
#define N1P     (2*INNERP)    // 5504
#define LOG2E   1.4426950408889634f

typedef __bf16 bf16;
typedef bf16  bf16x8 __attribute__((ext_vector_type(8)));
typedef float f32x4  __attribute__((ext_vector_type(4)));
typedef uint32_t u32x4 __attribute__((ext_vector_type(4)));

__device__ inline f32x4 mfma16(bf16x8 a, bf16x8 b, f32x4 c) {
  return __builtin_amdgcn_mfma_f32_16x16x32_bf16(a, b, c, 0, 0, 0);
}

__device__ inline void gload_lds16(const void* g, void* l) {
  __builtin_amdgcn_global_load_lds(
      (const __attribute__((address_space(1))) void*)g,
      (__attribute__((address_space(3))) void*)l, 16, 0, 0);
}

// ---------------- weight conversion (vectorized stores) ----------------
__global__ void conv_bf16_kernel(const float* __restrict__ src, bf16* __restrict__ dst, size_t n) {
  size_t i = ((size_t)blockIdx.x * 256 + threadIdx.x) * 8;
  if (i >= n) return;
  float4 v0 = *(const float4*)(src + i);
  float4 v1 = *(const float4*)(src + i + 4);
  bf16x8 o = { (bf16)v0.x,(bf16)v0.y,(bf16)v0.z,(bf16)v0.w,
               (bf16)v1.x,(bf16)v1.y,(bf16)v1.z,(bf16)v1.w };
  *(bf16x8*)(dst + i) = o;
}

// ff_w1 (DEPTH,5460,1024) -> padded interleaved (DEPTH,5504,1024):
// padded row rp: p=rp>>4, w=rp&15, col=(p>>1)*16+w; even p -> a-row col,
// odd p -> gate-row INNER+col; col>=INNER -> zero.
__global__ void conv_w1_kernel(const float* __restrict__ src, bf16* __restrict__ dst) {
  size_t i = ((size_t)blockIdx.x * 256 + threadIdx.x) * 8;
  const size_t tot = (size_t)DEPTH * N1P * DMODEL;
  if (i >= tot) return;
  int d  = (int)(i / ((size_t)N1P * DMODEL));
  int rem = (int)(i % ((size_t)N1P * DMODEL));
  int rp = rem / DMODEL, k = rem % DMODEL;
  int p2 = rp >> 4, w = rp & 15;
  int col = ((p2 >> 1) << 4) + w;
  bf16x8 o;
  if (col >= INNER) {
    o = (bf16x8)(bf16)0.f;
  } else {
    int rs = (p2 & 1) ? (INNER + col) : col;
    const float* s = src + ((size_t)d * N1 + rs) * DMODEL + k;
    float4 v0 = *(const float4*)s;
    float4 v1 = *(const float4*)(s + 4);
    o = bf16x8{ (bf16)v0.x,(bf16)v0.y,(bf16)v0.z,(bf16)v0.w,
                (bf16)v1.x,(bf16)v1.y,(bf16)v1.z,(bf16)v1.w };
  }
  *(bf16x8*)(dst + i) = o;
}

__global__ void conv_b1_kernel(const float* __restrict__ src, float* __restrict__ dst) {
  int i = blockIdx.x * 256 + threadIdx.x;
  if (i >= DEPTH * N1P) return;
  int d = i / N1P, rp = i % N1P;
  int p2 = rp >> 4, w = rp & 15;
  int col = ((p2 >> 1) << 4) + w;
  float v = 0.f;
  if (col < INNER) v = src[d * N1 + ((p2 & 1) ? (INNER + col) : col)];
  dst[i] = v;
}

__global__ void conv_w2_kernel(const float* __restrict__ src, bf16* __restrict__ dst) {
  size_t i = ((size_t)blockIdx.x * 256 + threadIdx.x) * 8;
  const size_t tot = (size_t)DEPTH * DMODEL * INNERP;
  if (i >= tot) return;
  size_t dn = i / INNERP;
  int kp = (int)(i % INNERP);
  const float* s = src + dn * INNER;
  bf16x8 o;
  #pragma unroll
  for (int j = 0; j < 8; ++j) {
    int k = kp + j;
    o[j] = (k < INNER) ? (bf16)s[k] : (bf16)0.f;
  }
  *(bf16x8*)(dst + i) = o;
}

// ---------------- RMSNorm ----------------
template<bool OUT_BF16>
__global__ __launch_bounds__(256) void rmsnorm_kernel(const float* __restrict__ x,
    const float* __restrict__ gamma, void* __restrict__ out) {
  const int row = blockIdx.x;
  const int tid = threadIdx.x;
  const float4 v = *(const float4*)(x + (size_t)row * DMODEL + tid * 4);
  float ss = v.x*v.x + v.y*v.y + v.z*v.z + v.w*v.w;
  for (int m = 1; m < 64; m <<= 1) ss += __shfl_xor(ss, m);
  __shared__ float ws4[4];
  if ((tid & 63) == 0) ws4[tid >> 6] = ss;
  __syncthreads();
  float tot = ws4[0] + ws4[1] + ws4[2] + ws4[3];
  float scale = 32.0f / fmaxf(sqrtf(tot), 1e-12f);
  const float4 g = *(const float4*)(gamma + tid * 4);
  float o0 = v.x*scale*g.x, o1 = v.y*scale*g.y, o2 = v.z*scale*g.z, o3 = v.w*scale*g.w;
  size_t p = (size_t)row * DMODEL + tid * 4;
  if (OUT_BF16) {
    bf16* ob = (bf16*)out;
    ob[p+0] = (bf16)o0; ob[p+1] = (bf16)o1; ob[p+2] = (bf16)o2; ob[p+3] = (bf16)o3;
  } else {
    *(float4*)((float*)out + p) = make_float4(o0, o1, o2, o3);
  }
}

// ---------------- GEMM: C(MxN) = A(MxK) @ W(NxK)^T + bias [+ res] ----------------
// Double-buffered LDS + prefetch (T3-minimum) + XOR chunk swizzle (T2,
// both-sides: pre-swizzled global source for global_load_lds, swizzled
// ds_read address). Physical 16B chunk = logical chunk ^ (row & 7).
// EPI: 0 = bf16 out, 1 = f32 out + residual add, 2 = fused GEGLU.
template<int TN, int EPI>
__global__ __launch_bounds__(256) void gemm_bt(const bf16* __restrict__ A,
    const bf16* __restrict__ Bw, const float* __restrict__ bias,
    const float* __restrict__ res, void* __restrict__ Cout,
    int M_, int N_, int K_) {
  constexpr int NFR = TN / 32;
  constexpr int BCH = TN / 32;
  __shared__ __attribute__((aligned(16))) bf16 As[2][128 * 64];
  __shared__ __attribute__((aligned(16))) bf16 Bs[2][TN * 64];
  const int tid  = threadIdx.x;
  const int lane = tid & 63;
  const int wid  = tid >> 6;
  const int wr = wid >> 1, wc = wid & 1;
  const int m0 = blockIdx.y * 128;
  const int n0 = blockIdx.x * TN;
  const int q = lane & 15, G = lane >> 4;
  const int s7 = q & 7;                       // fragment-row & 7
  const int srow = tid >> 3;                  // staging row within 32-row slab
  const int scol = ((tid & 7) ^ (srow & 7)) << 3;  // pre-swizzled source col

  f32x4 acc[4][NFR] = {};
  const int nk = K_ >> 6;

  auto stage = [&](int buf, int kt) {
    const int k0 = kt << 6;
    #pragma unroll
    for (int j = 0; j < 4; ++j) {
      gload_lds16(A + (size_t)(m0 + j*32 + srow) * K_ + k0 + scol,
                  &As[buf][(j * 256 + wid * 64) << 3]);
    }
    #pragma unroll
    for (int j = 0; j < BCH; ++j) {
      gload_lds16(Bw + (size_t)(n0 + j*32 + srow) * K_ + k0 + scol,
                  &Bs[buf][(j * 256 + wid * 64) << 3]);
    }
  };

  stage(0, 0);
  asm volatile("s_waitcnt vmcnt(0)" ::: "memory");
  __syncthreads();

  int cur = 0;
  for (int kt = 0; kt < nk; ++kt) {
    if (kt + 1 < nk) stage(cur ^ 1, kt + 1);
    #pragma unroll
    for (int kk = 0; kk < 2; ++kk) {
      const int c0 = kk * 4 + G;
      bf16x8 af[4], bfr[NFR];
      #pragma unroll
      for (int m = 0; m < 4; ++m)
        af[m] = *(const bf16x8*)(&As[cur][(wr*64 + m*16 + q) * 64 + ((c0 ^ s7) << 3)]);
      #pragma unroll
      for (int n = 0; n < NFR; ++n)
        bfr[n] = *(const bf16x8*)(&Bs[cur][(wc*(TN/2) + n*16 + q) * 64 + ((c0 ^ s7) << 3)]);
      #pragma unroll
      for (int m = 0; m < 4; ++m)
        #pragma unroll
        for (int n = 0; n < NFR; ++n)
          acc[m][n] = mfma16(af[m], bfr[n], acc[m][n]);
    }
    asm volatile("s_waitcnt vmcnt(0)" ::: "memory");
    __syncthreads();
    cur ^= 1;
  }

  const int rb = G << 2;
  const int cl = q;
  if (EPI == 2) {
    #pragma unroll
    for (int m = 0; m < 4; ++m) {
      #pragma unroll
      for (int np = 0; np < NFR/2; ++np) {
        int ca = n0 + wc*(TN/2) + (2*np)*16 + cl;
        int cg = ca + 16;
        float ba = bias[ca], bg = bias[cg];
        int colo = ((ca >> 5) << 4) + cl;
        #pragma unroll
        for (int r = 0; r < 4; ++r) {
          int row = m0 + wr*64 + m*16 + rb + r;
          float av = acc[m][2*np][r] + ba;
          float gv = acc[m][2*np+1][r] + bg;
          float gl = 0.5f * gv * (1.f + erff(gv * 0.70710678118654752f));
          ((bf16*)Cout)[(size_t)row * (N_ >> 1) + colo] = (bf16)(av * gl);
        }
      }
    }
  } else {
    #pragma unroll
    for (int m = 0; m < 4; ++m) {
      #pragma unroll
      for (int n = 0; n < NFR; ++n) {
        int col = n0 + wc*(TN/2) + n*16 + cl;
        float bv = bias[col];
        #pragma unroll
        for (int r = 0; r < 4; ++r) {
          int row = m0 + wr*64 + m*16 + rb + r;
          float v = acc[m][n][r] + bv;
          size_t p = (size_t)row * N_ + col;
          if (EPI == 1) ((float*)Cout)[p] = v + res[p];
          else          ((bf16*)Cout)[p] = (bf16)v;
        }
      }
    }
  }
}

// ---------------- Flash attention, split-KV=2, ALiBi, KVBLK=64 ----------------
__global__ __launch_bounds__(256) void attn_kernel(const bf16* __restrict__ qkv,
    const float* __restrict__ slopes, float* __restrict__ Opart, float* __restrict__ ml) {
  const int tid = threadIdx.x, lane = tid & 63, wid = tid >> 6;
  const int bh = blockIdx.y;
  const int b = bh >> 4, h = bh & 15;
  const int kvz = blockIdx.z;
  const int kv0 = kvz * (LSEQ/2);
  const float slope2 = slopes[h] * LOG2E;
  const float SC = 0.125f * LOG2E;
  const int qw = blockIdx.x * 64 + wid * 16;

  __shared__ __attribute__((aligned(16))) bf16     Kt[64 * 72];
  __shared__ __attribute__((aligned(16))) uint32_t V32[64 * 36];
  __shared__ __attribute__((aligned(16))) uint32_t Pl32[4][16 * 36];

  const size_t rs = 3 * DMODEL;
  const size_t base = (size_t)b * LSEQ * rs;

  bf16x8 qf[2];
  {
    const bf16* p = qkv + base + (size_t)(qw + (lane & 15)) * rs + h * HDIM + ((lane >> 4) << 3);
    qf[0] = *(const bf16x8*)p;
    qf[1] = *(const bf16x8*)(p + 32);
  }

  f32x4 accO[4] = {};
  float mrow[4], lrow[4];
  #pragma unroll
  for (int r = 0; r < 4; ++r) { mrow[r] = -1e30f; lrow[r] = 0.f; }

  const int trow = tid >> 2;
  const int tcol = (tid & 3) << 4;

  bf16x8 kreg0, kreg1, vreg0, vreg1;
  {
    const bf16* kp = qkv + base + (size_t)(kv0 + trow) * rs + DMODEL + h * HDIM + tcol;
    kreg0 = *(const bf16x8*)kp; kreg1 = *(const bf16x8*)(kp + 8);
    const bf16* vp = qkv + base + (size_t)(kv0 + trow) * rs + 2 * DMODEL + h * HDIM + tcol;
    vreg0 = *(const bf16x8*)vp; vreg1 = *(const bf16x8*)(vp + 8);
  }

  uint32_t* P32w = &Pl32[wid][0];
  const int q = lane & 15, G = lane >> 4;

  for (int kv = kv0; kv < kv0 + LSEQ/2; kv += 64) {
    __syncthreads();
    *(bf16x8*)(Kt + trow * 72 + tcol)     = kreg0;
    *(bf16x8*)(Kt + trow * 72 + tcol + 8) = kreg1;
    {
      u32x4 va = __builtin_bit_cast(u32x4, vreg0);
      u32x4 vb = __builtin_bit_cast(u32x4, vreg1);
      u32x4 pa, pb;
      #pragma unroll
      for (int i = 0; i < 4; ++i) {
        pa[i] = (uint32_t)__shfl_xor((int)va[i], 4);
        pb[i] = (uint32_t)__shfl_xor((int)vb[i], 4);
      }
      const bool oddk = (trow & 1);
      const int d0 = tcol + (oddk ? 8 : 0);
      u32x4 m = oddk ? vb : va;
      u32x4 oo = oddk ? pb : pa;
      const int kpair = trow >> 1;
      const int swz = kpair ^ ((d0 >> 3) << 1);
      #pragma unroll
      for (int i = 0; i < 4; ++i) {
        uint32_t lo = oddk ? oo[i] : m[i];
        uint32_t hi = oddk ? m[i] : oo[i];
        uint32_t w0 = (lo & 0xffffu) | (hi << 16);
        uint32_t w1 = (lo >> 16) | (hi & 0xffff0000u);
        V32[(d0 + 2*i)     * 36 + swz] = w0;
        V32[(d0 + 2*i + 1) * 36 + swz] = w1;
      }
    }
    __syncthreads();

    if (kv + 64 < kv0 + LSEQ/2) {
      const bf16* kp = qkv + base + (size_t)(kv + 64 + trow) * rs + DMODEL + h * HDIM + tcol;
      kreg0 = *(const bf16x8*)kp; kreg1 = *(const bf16x8*)(kp + 8);
      const bf16* vp = qkv + base + (size_t)(kv + 64 + trow) * rs + 2 * DMODEL + h * HDIM + tcol;
      vreg0 = *(const bf16x8*)vp; vreg1 = *(const bf16x8*)(vp + 8);
    }

    f32x4 sacc[4] = {};
    __builtin_amdgcn_s_setprio(1);
    #pragma unroll
    for (int nt = 0; nt < 4; ++nt) {
      const bf16* kb = Kt + (nt * 16 + q) * 72 + (G << 3);
      sacc[nt] = mfma16(qf[0], *(const bf16x8*)kb, sacc[nt]);
      sacc[nt] = mfma16(qf[1], *(const bf16x8*)(kb + 32), sacc[nt]);
    }
    __builtin_amdgcn_s_setprio(0);

    float pv[4][4];
    #pragma unroll
    for (int r = 0; r < 4; ++r) {
      int qi = qw + (G << 2) + r;
      float vmax = -1e30f;
      #pragma unroll
      for (int nt = 0; nt < 4; ++nt) {
        int kj = kv + nt * 16 + q;
        float s = sacc[nt][r] * SC - slope2 * fabsf((float)(qi - kj));
        pv[nt][r] = s;
        vmax = fmaxf(vmax, s);
      }
      for (int m = 1; m < 16; m <<= 1) vmax = fmaxf(vmax, __shfl_xor(vmax, m));
      float newmax = fmaxf(mrow[r], vmax);
      float ef = exp2f(mrow[r] - newmax);
      float rsum = 0.f;
      #pragma unroll
      for (int nt = 0; nt < 4; ++nt) {
        float p = exp2f(pv[nt][r] - newmax);
        pv[nt][r] = p;
        rsum += p;
      }
      for (int m = 1; m < 16; m <<= 1) rsum += __shfl_xor(rsum, m);
      lrow[r] = lrow[r] * ef + rsum;
      mrow[r] = newmax;
      #pragma unroll
      for (int dn = 0; dn < 4; ++dn) accO[dn][r] *= ef;
    }

    #pragma unroll
    for (int nt = 0; nt < 4; ++nt) {
      #pragma unroll
      for (int r = 0; r < 4; ++r) {
        float other = __shfl_xor(pv[nt][r], 1);
        if (!(lane & 1)) {
          uint32_t w;
          asm("v_cvt_pk_bf16_f32 %0, %1, %2" : "=v"(w) : "v"(pv[nt][r]), "v"(other));
          int prow = (G << 2) + r;
          int col2 = nt * 8 + (q >> 1);
          P32w[prow * 36 + (col2 ^ ((prow & 7) << 1))] = w;
        }
      }
    }
    asm volatile("s_waitcnt lgkmcnt(0)" ::: "memory");

    __builtin_amdgcn_s_setprio(1);
    #pragma unroll
    for (int chunk = 0; chunk < 2; ++chunk) {
      u32x4 praw = *(const u32x4*)(P32w + q * 36 + chunk * 16 + 4 * (G ^ ((q >> 1) & 3)));
      if (q & 1) praw = __builtin_shufflevector(praw, praw, 2, 3, 0, 1);
      bf16x8 pf = __builtin_bit_cast(bf16x8, praw);
      #pragma unroll
      for (int dn = 0; dn < 4; ++dn) {
        const int d = dn * 16 + q;
        u32x4 raw = *(const u32x4*)(V32 + d * 36 + chunk * 16 + 4 * (G ^ dn));
        if ((lane >> 3) & 1) raw = __builtin_shufflevector(raw, raw, 2, 3, 0, 1);
        bf16x8 vf = __builtin_bit_cast(bf16x8, raw);
        accO[dn] = mfma16(pf, vf, accO[dn]);
      }
    }
    __builtin_amdgcn_s_setprio(0);
  }

  #pragma unroll
  for (int r = 0; r < 4; ++r) {
    int qr = qw + (G << 2) + r;
    size_t obase = ((size_t)(kvz * 32 + bh) * LSEQ + qr) * HDIM;
    #pragma unroll
    for (int dn = 0; dn < 4; ++dn)
      Opart[obase + dn * 16 + q] = accO[dn][r];
    if (q == 0) {
      size_t mb = ((size_t)(kvz * 32 + bh) * LSEQ + qr) * 2;
      ml[mb]     = mrow[r];
      ml[mb + 1] = lrow[r];
    }
  }
}

// combine two kv-halves
__global__ __launch_bounds__(256) void attn_combine(const float* __restrict__ Opart,
    const float* __restrict__ ml, bf16* __restrict__ o) {
  int idx = blockIdx.x * 256 + threadIdx.x;
  int bh = idx >> 14;
  int rem = idx & 16383;
  int qr = rem >> 4;
  int d4 = (rem & 15) << 2;
  size_t r0 = (size_t)bh * LSEQ + qr;
  size_t r1 = (size_t)(32 + bh) * LSEQ + qr;
  float m0 = ml[r0*2], l0 = ml[r0*2+1];
  float m1 = ml[r1*2], l1 = ml[r1*2+1];
  float m = fmaxf(m0, m1);
  float w0 = exp2f(m0 - m), w1 = exp2f(m1 - m);
  float inv = 1.f / (l0 * w0 + l1 * w1);
  float4 o0 = *(const float4*)(Opart + r0 * HDIM + d4);
  float4 o1 = *(const float4*)(Opart + r1 * HDIM + d4);
  int b = bh >> 4, h = bh & 15;
  bf16* op = o + ((size_t)(b * LSEQ + qr) * DMODEL + h * HDIM + d4);
  op[0] = (bf16)((o0.x*w0 + o1.x*w1) * inv);
  op[1] = (bf16)((o0.y*w0 + o1.y*w1) * inv);
  op[2] = (bf16)((o0.z*w0 + o1.z*w1) * inv);
  op[3] = (bf16)((o0.w*w0 + o1.w*w1) * inv);
}

// ---------------- host ----------------
extern "C" void kernel_launch(void* const* d_in, const int* in_sizes, int n_in,
                              void* d_out, int out_size, void* d_ws, size_t ws_size,
                              hipStream_t stream) {
  const float* x_in      = (const float*)d_in[0];
  const float* slopes    = (const float*)d_in[1];
  const float* g_attn    = (const float*)d_in[2];
  const float* w_in      = (const float*)d_in[3];
  const float* b_in      = (const float*)d_in[4];
  const float* w_out     = (const float*)d_in[5];
  const float* b_out     = (const float*)d_in[6];
  const float* g_ff      = (const float*)d_in[7];
  const float* w1        = (const float*)d_in[8];
  const float* b1        = (const float*)d_in[9];
  const float* w2        = (const float*)d_in[10];
  const float* b2        = (const float*)d_in[11];
  const float* g_final   = (const float*)d_in[12];

  char* p = (char*)d_ws;
  float* xw   = (float*)p;              p += (size_t)MROWS * DMODEL * 4;
  bf16* abuf  = (bf16*)p;               p += (size_t)MROWS * DMODEL * 2;
  bf16* qkvb  = (bf16*)p;               p += (size_t)MROWS * 3 * DMODEL * 2;
  bf16* obuf  = (bf16*)p;               p += (size_t)MROWS * DMODEL * 2;
  bf16* gbuf  = (bf16*)p;               p += (size_t)MROWS * INNERP * 2;
  float* Opart = (float*)p;             p += (size_t)2 * 32 * LSEQ * HDIM * 4;
  float* mlb   = (float*)p;             p += (size_t)2 * 32 * LSEQ * 2 * 4;
  bf16* w_in_b  = (bf16*)p;             p += (size_t)DEPTH * 3 * DMODEL * DMODEL * 2;
  bf16* w_out_b = (bf16*)p;             p += (size_t)DEPTH * DMODEL * DMODEL * 2;
  bf16* w1p     = (bf16*)p;             p += (size_t)DEPTH * N1P * DMODEL * 2;
  bf16* w2p     = (bf16*)p;             p += (size_t)DEPTH * DMODEL * INNERP * 2;
  float* b1p    = (float*)p;            p += (size_t)DEPTH * N1P * 4;

  hipMemcpyAsync(xw, x_in, (size_t)MROWS * DMODEL * 4, hipMemcpyDeviceToDevice, stream);

  conv_bf16_kernel<<<6144, 256, 0, stream>>>(w_in, w_in_b, (size_t)DEPTH * 3 * DMODEL * DMODEL);
  conv_bf16_kernel<<<2048, 256, 0, stream>>>(w_out, w_out_b, (size_t)DEPTH * DMODEL * DMODEL);
  conv_w1_kernel<<<11008, 256, 0, stream>>>(w1, w1p);
  conv_b1_kernel<<<86, 256, 0, stream>>>(b1, b1p);
  conv_w2_kernel<<<5504, 256, 0, stream>>>(w2, w2p);

  for (int i = 0; i < DEPTH; ++i) {
    rmsnorm_kernel<true><<<MROWS, 256, 0, stream>>>(xw, g_attn + i * DMODEL, abuf);
    gemm_bt<64, 0><<<dim3(48, 16), 256, 0, stream>>>(
        abuf, w_in_b + (size_t)i * 3 * DMODEL * DMODEL, b_in + i * 3 * DMODEL,
        nullptr, qkvb, MROWS, 3 * DMODEL, DMODEL);
    attn_kernel<<<dim3(16, 32, 2), 256, 0, stream>>>(qkvb, slopes, Opart, mlb);
    attn_combine<<<2048, 256, 0, stream>>>(Opart, mlb, obuf);
    gemm_bt<64, 1><<<dim3(16, 16), 256, 0, stream>>>(
        obuf, w_out_b + (size_t)i * DMODEL * DMODEL, b_out + i * DMODEL,
        xw, xw, MROWS, DMODEL, DMODEL);
    rmsnorm_kernel<true><<<MROWS, 256, 0, stream>>>(xw, g_ff + i * DMODEL, abuf);
    gemm_bt<128, 2><<<dim3(43, 16), 256, 0, stream>>>(
        abuf, w1p + (size_t)i * N1P * DMODEL, b1p + i * N1P,
        nullptr, gbuf, MROWS, N1P, DMODEL);
    gemm_bt<64, 1><<<dim3(16, 16), 256, 0, stream>>>(
        gbuf, w2p + (size_t)i * DMODEL * INNERP, b2 + i * DMODEL,
        xw, xw, MROWS, DMODEL, INNERP);
  }
  rmsnorm_kernel<false><<<MROWS, 256, 0, stream>>>(xw, g_final, d_out);
}